// Round 6
// baseline (886.699 us; speedup 1.0000x reference)
//
#include <hip/hip_runtime.h>
#include <math.h>

#define IMG_W 512
#define IMG_H 512
#define NPLANES 48      // 16 * 3
#define RROWS 32        // output rows per block (512 = 32*16 exact)
#define NCHUNK 16
#define NSTRIP 8        // 512 / 64 cols
#define NBLOCKS (NPLANES * NSTRIP * NCHUNK)   // 6144
#define SSIM_C1 1e-4f
#define SSIM_C2 9e-4f

typedef float v2f __attribute__((ext_vector_type(2)));

struct GW { float g[11]; };

__device__ __forceinline__ float fdiv_fast(float n, float d) {
  float r = __builtin_amdgcn_rcpf(d);
  r = r * fmaf(-d, r, 2.0f);      // 1 Newton step on reciprocal
  float q = n * r;
  q = fmaf(fmaf(-d, q, n), r, q); // residual correction
  return q;
}

// One wave per block; 64 output cols x 32 output rows. TWO image rows per
// phase: LDS rows are row-pair v2f (ds_read count halved), horizontal conv
// is packed fp32 (v_pk_fma_f32, the biggest VALU block). Ring, vertical
// conv, epilogue, masking and reduction are byte-identical to the round-5
// verified scalar code (ring slot = input-row-index mod 11; row 2p -> slot
// (2ph)%11, row 2p+1 -> (2ph+1)%11; vconv reads (2ph+1+k)%11 / (2ph+2+k)%11).
// NO launch_bounds: every explicit bound so far made allocation worse
// (R2 default=100 VGPR best; (64,2)->88+regress; (256,3)->scratch spill).
__global__ void ssim_main(
    const float* __restrict__ A, const float* __restrict__ B,
    const float* __restrict__ F, double* __restrict__ partials, GW gw)
{
  __shared__ v2f sA[2][80], sB[2][80], sF[2][80];   // {row 2p, row 2p+1}
  const int b = blockIdx.x;
  const int plane = b / (NSTRIP * NCHUNK);
  const int rem   = b % (NSTRIP * NCHUNK);
  const int strip = rem / NCHUNK;
  const int chunk = rem % NCHUNK;
  const int x0 = strip * 64;
  const int y0 = chunk * RROWS;
  const int t = threadIdx.x;
  const size_t pbase = (size_t)plane * (IMG_W * IMG_H);
  const float* Ap = A + pbase;
  const float* Bp = B + pbase;
  const float* Fp = F + pbase;

  const int c  = x0 - 5 + t;                 // primary load column
  const bool cok = (c >= 0) && (c < IMG_W);
  const int c2 = c + 64;                     // halo column (lanes 0..9)
  const bool c2ok = (t < 10) && (c2 < IMG_W);

  // ring[stream][slot]: hconv'd rows, slot = input-row-index mod 11.
  // 7 streams: A, B, F, (A^2+F^2), (B^2+F^2), AF, BF (merge verified R4/R5).
  float ring[7][11];
  #pragma unroll
  for (int s = 0; s < 7; ++s)
    #pragma unroll
    for (int k = 0; k < 11; ++k) ring[s][k] = 0.f;

  float acc = 0.f;

  // prefetch registers: rows (0,1) of the pair, primary + halo
  float rA0,rB0,rF0,xA0,xB0,xF0, rA1,rB1,rF1,xA1,xB1,xF1;
  auto load_pair = [&](int p) {
    const int yin0 = y0 - 5 + 2 * p, yin1 = yin0 + 1;
    const bool rok0 = (yin0 >= 0) && (yin0 < IMG_H);
    const bool rok1 = (yin1 >= 0) && (yin1 < IMG_H);
    const size_t o0 = (size_t)yin0 * IMG_W, o1 = (size_t)yin1 * IMG_W;
    rA0 = (rok0 && cok) ? Ap[o0 + c] : 0.f;
    rB0 = (rok0 && cok) ? Bp[o0 + c] : 0.f;
    rF0 = (rok0 && cok) ? Fp[o0 + c] : 0.f;
    xA0 = (rok0 && c2ok) ? Ap[o0 + c2] : 0.f;
    xB0 = (rok0 && c2ok) ? Bp[o0 + c2] : 0.f;
    xF0 = (rok0 && c2ok) ? Fp[o0 + c2] : 0.f;
    rA1 = (rok1 && cok) ? Ap[o1 + c] : 0.f;
    rB1 = (rok1 && cok) ? Bp[o1 + c] : 0.f;
    rF1 = (rok1 && cok) ? Fp[o1 + c] : 0.f;
    xA1 = (rok1 && c2ok) ? Ap[o1 + c2] : 0.f;
    xB1 = (rok1 && c2ok) ? Bp[o1 + c2] : 0.f;
    xF1 = (rok1 && c2ok) ? Fp[o1 + c2] : 0.f;
  };

  load_pair(0);   // preload rows 0,1

  for (int jj = 0; jj < 2; ++jj) {
    #pragma unroll
    for (int ph = 0; ph < 11; ++ph) {
      const int p = jj * 11 + ph;            // row-pair index; rows 2p,2p+1
      if (p <= 20) {                         // rows 0..41 staged
        const int buf = p & 1;
        // --- stage prefetched row pair into LDS (double-buffered) ---
        sA[buf][t] = (v2f){rA0, rA1};
        sB[buf][t] = (v2f){rB0, rB1};
        sF[buf][t] = (v2f){rF0, rF1};
        if (t < 10) {
          sA[buf][t+64] = (v2f){xA0, xA1};
          sB[buf][t+64] = (v2f){xB0, xB1};
          sF[buf][t+64] = (v2f){xF0, xF1};
        }
        // --- issue NEXT pair's global loads; latency hidden under convs ---
        if (p < 20) load_pair(p + 1);

        // --- packed horizontal 11-tap conv, 7 streams, both rows at once ---
        v2f hA={0,0},hB={0,0},hF={0,0},hS1={0,0},hS2={0,0},hAF={0,0},hBF={0,0};
        #pragma unroll
        for (int k = 0; k < 11; ++k) {
          const float wt = gw.g[k];
          const v2f a = sA[buf][t+k], bb = sB[buf][t+k], f = sF[buf][t+k];
          const v2f wa = wt*a, wb = wt*bb, wf = wt*f;
          hA += wa; hB += wb; hF += wf;
          hS1 += wa*a; hS1 += wf*f;          // conv(A^2 + F^2)
          hS2 += wb*bb; hS2 += wf*f;         // conv(B^2 + F^2)
          hAF += wa*f; hBF += wb*f;
        }

        const int s0 = (2 * ph) % 11;        // slot of row 2p  (22*jj == 0 mod 11)
        const int s1 = (2 * ph + 1) % 11;    // slot of row 2p+1

        // row 2p -> ring, then its vconv (rows 2p-10..2p live)
        ring[0][s0]=hA.x; ring[1][s0]=hB.x; ring[2][s0]=hF.x;
        ring[3][s0]=hS1.x; ring[4][s0]=hS2.x; ring[5][s0]=hAF.x; ring[6][s0]=hBF.x;
        if (p >= 5) {
          float m[7];
          #pragma unroll
          for (int s = 0; s < 7; ++s) m[s] = 0.f;
          #pragma unroll
          for (int k = 0; k < 11; ++k) {
            const int sl = (2 * ph + 1 + k) % 11;   // row (2p-10+k)
            const float wt = gw.g[k];
            #pragma unroll
            for (int s = 0; s < 7; ++s) m[s] = fmaf(wt, ring[s][sl], m[s]);
          }
          const float mA=m[0], mB=m[1], mF=m[2];
          const float vS1=m[3], vS2=m[4], vAF=m[5], vBF=m[6];
          const float mA2=mA*mA, mB2=mB*mB, mF2=mF*mF, mAF=mA*mF, mBF=mB*mF;
          const float sAF = vAF - mAF, sBF = vBF - mBF;
          const float ts1 = vS1 - mA2 - mF2;
          const float ts2 = vS2 - mB2 - mF2;
          const float n1 = fmaf(2.f, mAF, SSIM_C1) * fmaf(2.f, sAF, SSIM_C2);
          const float d1 = (mA2 + mF2 + SSIM_C1) * (ts1 + SSIM_C2);
          const float n2 = fmaf(2.f, mBF, SSIM_C1) * fmaf(2.f, sBF, SSIM_C2);
          const float d2 = (mB2 + mF2 + SSIM_C1) * (ts2 + SSIM_C2);
          acc += fdiv_fast(n1, d1) + fdiv_fast(n2, d2);
        }

        // row 2p+1 -> ring, then its vconv (rows 2p-9..2p+1 live)
        ring[0][s1]=hA.y; ring[1][s1]=hB.y; ring[2][s1]=hF.y;
        ring[3][s1]=hS1.y; ring[4][s1]=hS2.y; ring[5][s1]=hAF.y; ring[6][s1]=hBF.y;
        if (p >= 5) {
          float m[7];
          #pragma unroll
          for (int s = 0; s < 7; ++s) m[s] = 0.f;
          #pragma unroll
          for (int k = 0; k < 11; ++k) {
            const int sl = (2 * ph + 2 + k) % 11;   // row (2p-9+k)
            const float wt = gw.g[k];
            #pragma unroll
            for (int s = 0; s < 7; ++s) m[s] = fmaf(wt, ring[s][sl], m[s]);
          }
          const float mA=m[0], mB=m[1], mF=m[2];
          const float vS1=m[3], vS2=m[4], vAF=m[5], vBF=m[6];
          const float mA2=mA*mA, mB2=mB*mB, mF2=mF*mF, mAF=mA*mF, mBF=mB*mF;
          const float sAF = vAF - mAF, sBF = vBF - mBF;
          const float ts1 = vS1 - mA2 - mF2;
          const float ts2 = vS2 - mB2 - mF2;
          const float n1 = fmaf(2.f, mAF, SSIM_C1) * fmaf(2.f, sAF, SSIM_C2);
          const float d1 = (mA2 + mF2 + SSIM_C1) * (ts1 + SSIM_C2);
          const float n2 = fmaf(2.f, mBF, SSIM_C1) * fmaf(2.f, sBF, SSIM_C2);
          const float d2 = (mB2 + mF2 + SSIM_C1) * (ts2 + SSIM_C2);
          acc += fdiv_fast(n1, d1) + fdiv_fast(n2, d2);
        }
      }
    }
  }

  // wave (64-lane) reduction, one plain store per block
  float wsum = acc;
  #pragma unroll
  for (int off = 32; off > 0; off >>= 1)
    wsum += __shfl_down(wsum, off, 64);
  if (t == 0) partials[b] = (double)wsum;
}

__global__ __launch_bounds__(256) void ssim_final(
    const double* __restrict__ partials, float* __restrict__ out)
{
  __shared__ double sd[256];
  const int t = threadIdx.x;
  double s = 0.0;
  for (int i = t; i < NBLOCKS; i += 256) s += partials[i];
  sd[t] = s;
  __syncthreads();
  for (int off = 128; off > 0; off >>= 1) {
    if (t < off) sd[t] += sd[t + off];
    __syncthreads();
  }
  if (t == 0)
    out[0] = (float)(0.5 * sd[0] / (double)(16.0 * 3.0 * 512.0 * 512.0));
}

extern "C" void kernel_launch(void* const* d_in, const int* in_sizes, int n_in,
                              void* d_out, int out_size, void* d_ws, size_t ws_size,
                              hipStream_t stream) {
  const float* A = (const float*)d_in[0];
  const float* B = (const float*)d_in[1];
  const float* F = (const float*)d_in[2];
  double* partials = (double*)d_ws;   // NBLOCKS doubles = 48 KB

  GW gw;
  double g[11], s = 0.0;
  for (int i = 0; i < 11; ++i) { g[i] = exp(-((double)((i-5)*(i-5))) / 4.5); s += g[i]; }
  for (int i = 0; i < 11; ++i) gw.g[i] = (float)(g[i] / s);

  hipLaunchKernelGGL(ssim_main, dim3(NBLOCKS), dim3(64), 0, stream,
                     A, B, F, partials, gw);
  hipLaunchKernelGGL(ssim_final, dim3(1), dim3(256), 0, stream,
                     partials, (float*)d_out);
}